// Round 18
// baseline (1280.525 us; speedup 1.0000x reference)
//
#include <hip/hip_runtime.h>
#include <hip/hip_bf16.h>

typedef unsigned short u16;
typedef unsigned int u32;
typedef unsigned long long u64;
typedef __bf16 bf16x8 __attribute__((ext_vector_type(8)));
typedef float f32x4 __attribute__((ext_vector_type(4)));

#define NB 64
#define NT 128
#define NF 1024
#define NH 1024
#define NK 2048
#define NG 4096
#define NBH (NB * NH)

#define FSTR 16   // flags: one u32 per 64B line

// LDS: W slice 128 KiB + zsx[2 buf][2][64][17] + zsh[2][64][17]
#define W_LDS_BYTES 131072
#define ZSX_BYTES (2 * 2 * 64 * 17 * 4)   // 17408
#define ZSH_BYTES (2 * 64 * 17 * 4)       // 8704
#define SMEM_BYTES (W_LDS_BYTES + ZSX_BYTES + ZSH_BYTES + 64)  // 157248

__device__ __forceinline__ u16 f2bf(float f) {
  unsigned u = __builtin_bit_cast(unsigned, f);
  u = (u + 0x7FFFu + ((u >> 16) & 1u)) >> 16;
  return (u16)u;
}
__device__ __forceinline__ float bf2f(u16 v) {
  unsigned u = ((unsigned)v) << 16;
  return __builtin_bit_cast(float, u);
}
// fast tanh: 1 - 2/(e^{2x}+1); exact limits at +-inf, err ~1e-7
__device__ __forceinline__ float ftanh(float x) {
  float e = __expf(2.f * x);
  return 1.f - 2.f / (e + 1.f);
}

// ---------------- prep: x fp32 -> bf16 ----------------
__global__ __launch_bounds__(256) void lstm_cvt_x(const float* __restrict__ x,
                                                  u16* __restrict__ xb) {
  int i = (blockIdx.x * 256 + threadIdx.x) * 4;
  float4 v = *reinterpret_cast<const float4*>(x + i);
  ushort4 o;
  o.x = f2bf(v.x); o.y = f2bf(v.y); o.z = f2bf(v.z); o.w = f2bf(v.w);
  *reinterpret_cast<ushort4*>(xb + i) = o;
}

// ---------------- prep: W -> per-block LDS-image slices (verified R3-R15) ----
__global__ __launch_bounds__(256) void lstm_prep_w(const float* __restrict__ W,
                                                   u16* __restrict__ wt_blk) {
  __shared__ float tile[32][33];
  int n0 = blockIdx.x * 32;
  int k0 = blockIdx.y * 32;
  int tc = threadIdx.x & 31;
  int tr = threadIdx.x >> 5;
#pragma unroll
  for (int i = 0; i < 4; ++i) {
    int k = tr + i * 8;
    tile[k][tc] = W[(size_t)(k0 + k) * NG + n0 + tc];
  }
  __syncthreads();
#pragma unroll
  for (int i = 0; i < 4; ++i) {
    int n = n0 + tr + i * 8;
    float wv = tile[tc][tr + i * 8];
    int k = k0 + tc;
    int g = n >> 10, col = n & 1023;
    int b = col >> 2, brow = g * 4 + (col & 3);
    int kh = k >> 10, ch = (k & 1023) >> 5;
    int slot = (k >> 3) & 3, elem = k & 7;
    size_t base = (size_t)b * 65536 + (size_t)(kh * 32 + ch) * 512
                + (size_t)(slot * 16 + brow) * 8 + elem;
    u16 hi = f2bf(wv);
    wt_blk[base] = hi;
    wt_blk[base + 32768] = f2bf(wv - bf2f(hi));
  }
}

// x A-pass: 4 M-frags, K=256 slice, hi+lo MFMA, 2-stage pipeline (verified).
__device__ __forceinline__ void mfma_pass(const u16* __restrict__ a0, size_t rstride,
                                          const u16* __restrict__ Wl, int khalf,
                                          int kq, int lane, f32x4 acc[4]) {
  bf16x8 pf[4], qf[4];
#pragma unroll
  for (int i = 0; i < 4; ++i)
    pf[i] = *reinterpret_cast<const bf16x8*>(a0 + (size_t)i * 16 * rstride);
#pragma unroll
  for (int cc = 0; cc < 8; ++cc) {
    if (cc < 7) {
#pragma unroll
      for (int i = 0; i < 4; ++i)
        qf[i] = *reinterpret_cast<const bf16x8*>(a0 + (size_t)i * 16 * rstride + (cc + 1) * 32);
    }
    const int ch = kq * 8 + cc;
    const bf16x8 wh = *reinterpret_cast<const bf16x8*>(
        Wl + (size_t)(khalf * 32 + ch) * 512 + lane * 8);
    const bf16x8 wl2 = *reinterpret_cast<const bf16x8*>(
        Wl + (size_t)(64 + khalf * 32 + ch) * 512 + lane * 8);
#pragma unroll
    for (int i = 0; i < 4; ++i)
      acc[i] = __builtin_amdgcn_mfma_f32_16x16x32_bf16(pf[i], wh, acc[i], 0, 0, 0);
#pragma unroll
    for (int i = 0; i < 4; ++i)
      acc[i] = __builtin_amdgcn_mfma_f32_16x16x32_bf16(pf[i], wl2, acc[i], 0, 0, 0);
#pragma unroll
    for (int i = 0; i < 4; ++i) pf[i] = qf[i];
  }
}

// ---------------- persistent LSTM (R15 base + coalesced zo + per-wave flags) ----
// 256 blocks x 512 threads. Waves 0-3: x-GEMM one step ahead (zsx dbuf).
// Waves 4-7: poll flags -> slab h load -> MFMA -> zsh write/add (3 barriers).
// Pointwise on waves 0,1 (tid<128); each posts ITS OWN line-padded flag after
// its own 256B publish + drain (no LDS handshake). Consumers poll both flags.
// zo staging is per-block contiguous (1 KiB/block/step) -> 16 LLC lines.
__global__ __launch_bounds__(512) void lstm_persist(
    const u16* __restrict__ xb, u16* __restrict__ hseq,
    const u16* __restrict__ wt_blk, const float* __restrict__ bias,
    float* __restrict__ out, u32* __restrict__ flags,
    float* __restrict__ zo) {
  extern __shared__ char smem[];
  u16* Wl = (u16*)smem;
  float (*zsx)[2][64][17] = (float(*)[2][64][17])(smem + W_LDS_BYTES);
  float (*zsh)[64][17] = (float(*)[64][17])(smem + W_LDS_BYTES + ZSX_BYTES);

  const int b = blockIdx.x;
  const int tid = threadIdx.x;
  const int lane = tid & 63;
  const int w = tid >> 6;
  const bool is_x = (w < 4);
  const int kq = w & 3;

  // ---- load W slice (128 KiB) into LDS ----
  {
    const u16* src = wt_blk + (size_t)b * 65536;
#pragma unroll
    for (int it = 0; it < 16; ++it) {
      uint4 v = *reinterpret_cast<const uint4*>(src + (size_t)it * 4096 + tid * 8);
      *reinterpret_cast<uint4*>(Wl + (size_t)it * 4096 + tid * 8) = v;
    }
  }
  for (int i = tid; i < 2 * 64 * 17; i += 512) ((float*)zsh)[i] = 0.f;

  const int arow = lane & 15;
  const int kfr = 8 * (lane >> 4);
  const int kbase = kq * 256 + kfr;
  const int zn = lane & 15;
  const int mg = (lane >> 4) * 4;

  // pointwise ownership: tid<128 owns (prow, 2 cols)
  const int prow = tid >> 1;
  const int pc = (tid & 1) * 2;
  const int gc0 = b * 4 + pc;
  float bz[2][4];
  float creg[2] = {0.f, 0.f};
  if (tid < 128) {
#pragma unroll
    for (int j = 0; j < 2; ++j) {
      bz[j][0] = bias[gc0 + j];
      bz[j][1] = bias[NH + gc0 + j];
      bz[j][2] = bias[2 * NH + gc0 + j];
      bz[j][3] = bias[3 * NH + gc0 + j];
    }
  }
  __syncthreads();

  // ---- prologue: x-waves fill zsx[0] = zx(0) ----
  {
    f32x4 acc[4] = {};
    if (is_x) {
      const u16* a0 = xb + ((size_t)arow * NT + 0) * NF + kbase;
      mfma_pass(a0, (size_t)NT * NF, Wl, 0, kq, lane, acc);
      if (w < 2) {
#pragma unroll
        for (int i = 0; i < 4; ++i)
#pragma unroll
          for (int r = 0; r < 4; ++r) zsx[0][w][i * 16 + mg + r][zn] = acc[i][r];
      }
    }
    __syncthreads();
    if (is_x && w >= 2) {
#pragma unroll
      for (int i = 0; i < 4; ++i)
#pragma unroll
        for (int r = 0; r < 4; ++r) zsx[0][w - 2][i * 16 + mg + r][zn] += acc[i][r];
    }
    __syncthreads();
  }

#pragma unroll 1
  for (int t = 0; t < NT; ++t) {
    const int cb = t & 1;        // zsx buffer consumed this step
    const int nb = (t + 1) & 1;  // zsx buffer filled this step
    f32x4 acc[4] = {};

    if (is_x) {
      if (t < NT - 1) {
        const u16* a0 = xb + ((size_t)arow * NT + (t + 1)) * NF + kbase;
        mfma_pass(a0, (size_t)NT * NF, Wl, 0, kq, lane, acc);
      }
    } else {
      if (t > 0) {
        // poll BOTH per-wave flags of each of the 64 producers (paced)
        const u32* fp = flags + ((size_t)t * 256 + kq * 64 + lane) * 2 * FSTR;
        u32 v0 = __hip_atomic_load(fp, __ATOMIC_RELAXED, __HIP_MEMORY_SCOPE_AGENT);
        u32 v1 = __hip_atomic_load(fp + FSTR, __ATOMIC_RELAXED, __HIP_MEMORY_SCOPE_AGENT);
        while (!__all((v0 & v1) != 0)) {
          __builtin_amdgcn_s_sleep(1);
          v0 = __hip_atomic_load(fp, __ATOMIC_RELAXED, __HIP_MEMORY_SCOPE_AGENT);
          v1 = __hip_atomic_load(fp + FSTR, __ATOMIC_RELAXED, __HIP_MEMORY_SCOPE_AGENT);
        }
        // slab-layout h-GEMM (verified R14/R15)
        const u64* hb = reinterpret_cast<const u64*>(hseq) + (size_t)t * (256 * 64);
        const int sbase = kq * 64 + 2 * (lane >> 4);
        u64 plo[4], phi[4], qlo[4], qhi[4];
#pragma unroll
        for (int i = 0; i < 4; ++i) {
          plo[i] = hb[(size_t)sbase * 64 + arow + 16 * i];
          phi[i] = hb[(size_t)(sbase + 1) * 64 + arow + 16 * i];
        }
        __builtin_amdgcn_s_setprio(1);
#pragma unroll
        for (int cc = 0; cc < 8; ++cc) {
          if (cc < 7) {
            const int s = sbase + (cc + 1) * 8;
#pragma unroll
            for (int i = 0; i < 4; ++i) {
              qlo[i] = hb[(size_t)s * 64 + arow + 16 * i];
              qhi[i] = hb[(size_t)(s + 1) * 64 + arow + 16 * i];
            }
          }
          const int ch = kq * 8 + cc;
          const bf16x8 wh = *reinterpret_cast<const bf16x8*>(
              Wl + (size_t)(32 + ch) * 512 + lane * 8);             // kh=1 hi
          const bf16x8 wlo = *reinterpret_cast<const bf16x8*>(
              Wl + (size_t)(96 + ch) * 512 + lane * 8);             // kh=1 lo
#pragma unroll
          for (int i = 0; i < 4; ++i) {
            union HU { u64 q[2]; bf16x8 f; } u;
            u.q[0] = plo[i];
            u.q[1] = phi[i];
            acc[i] = __builtin_amdgcn_mfma_f32_16x16x32_bf16(u.f, wh, acc[i], 0, 0, 0);
            acc[i] = __builtin_amdgcn_mfma_f32_16x16x32_bf16(u.f, wlo, acc[i], 0, 0, 0);
          }
#pragma unroll
          for (int i = 0; i < 4; ++i) { plo[i] = qlo[i]; phi[i] = qhi[i]; }
        }
        __builtin_amdgcn_s_setprio(0);
      }
    }

    // ---- write phase ----
    if (is_x) {
      if (w < 2 && t < NT - 1) {
#pragma unroll
        for (int i = 0; i < 4; ++i)
#pragma unroll
          for (int r = 0; r < 4; ++r) zsx[nb][w][i * 16 + mg + r][zn] = acc[i][r];
      }
    } else {
      if (w < 6 && t > 0) {
#pragma unroll
        for (int i = 0; i < 4; ++i)
#pragma unroll
          for (int r = 0; r < 4; ++r) zsh[w - 4][i * 16 + mg + r][zn] = acc[i][r];
      }
    }
    __syncthreads();
    // ---- add phase ----
    if (is_x) {
      if (w >= 2 && t < NT - 1) {
#pragma unroll
        for (int i = 0; i < 4; ++i)
#pragma unroll
          for (int r = 0; r < 4; ++r) zsx[nb][w - 2][i * 16 + mg + r][zn] += acc[i][r];
      }
    } else {
      if (w >= 6 && t > 0) {
#pragma unroll
        for (int i = 0; i < 4; ++i)
#pragma unroll
          for (int r = 0; r < 4; ++r) zsh[w - 6][i * 16 + mg + r][zn] += acc[i][r];
      }
    }
    __syncthreads();

    // ---- fused pointwise + per-wave publish + coalesced staged output ----
    if (tid < 128) {
      float hn[2];
#pragma unroll
      for (int jj = 0; jj < 2; ++jj) {
        const int col = pc + jj;
        const float zi = zsx[cb][0][prow][col]      + zsx[cb][1][prow][col]      + zsh[0][prow][col]      + zsh[1][prow][col]      + bz[jj][0];
        const float zj = zsx[cb][0][prow][4 + col]  + zsx[cb][1][prow][4 + col]  + zsh[0][prow][4 + col]  + zsh[1][prow][4 + col]  + bz[jj][1];
        const float zf = zsx[cb][0][prow][8 + col]  + zsx[cb][1][prow][8 + col]  + zsh[0][prow][8 + col]  + zsh[1][prow][8 + col]  + bz[jj][2];
        const float zo4 = zsx[cb][0][prow][12 + col] + zsx[cb][1][prow][12 + col] + zsh[0][prow][12 + col] + zsh[1][prow][12 + col] + bz[jj][3];
        const float si = 1.f / (1.f + __expf(-zi));
        const float tj = ftanh(zj);
        const float sf = 1.f / (1.f + __expf(-(zf + 1.0f)));  // FORGET_BIAS = 1
        const float so = 1.f / (1.f + __expf(-zo4));
        const float cn = creg[jj] * sf + si * tj;
        hn[jj] = ftanh(cn) * so;
        creg[jj] = cn;
      }
      if (t < NT - 1) {
        // h publish: slab layout, this wave's 64 u32 = 256 B (4 LLC lines)
        u32 hv = (u32)f2bf(hn[0]) | ((u32)f2bf(hn[1]) << 16);
        u32* hp = reinterpret_cast<u32*>(hseq)
                + ((size_t)(t + 1) * 256 + b) * 128 + prow * 2 + (pc >> 1);
        __hip_atomic_store(hp, hv, __ATOMIC_RELAXED, __HIP_MEMORY_SCOPE_AGENT);
        asm volatile("s_waitcnt vmcnt(0)" ::: "memory");  // own 4-line ack
        // per-wave flag: wave 0 -> half 0, wave 1 -> half 1 (no handshake)
        if (lane == 0)
          __hip_atomic_store(
              &flags[(((size_t)(t + 1) * 256 + b) * 2 + w) * FSTR], 1u,
              __ATOMIC_RELAXED, __HIP_MEMORY_SCOPE_AGENT);
      }
      // staged output: per-block contiguous slab (1 KiB), float2 per thread
      {
        double d = __builtin_bit_cast(double, *reinterpret_cast<u64*>(hn));
        __hip_atomic_store(
            reinterpret_cast<u64*>(zo + ((size_t)t * 256 + b) * 256 + prow * 4 + pc),
            __builtin_bit_cast(u64, d), __ATOMIC_RELAXED, __HIP_MEMORY_SCOPE_AGENT);
      }
    }
    // h-waves proceed to poll step t+1 while waves 0-1 finish the tail
  }

  // ================= final: grid rendezvous, then zo -> out copy ==============
  __syncthreads();
  asm volatile("s_waitcnt vmcnt(0)" ::: "memory");  // all zo stores at LLC
  if (tid == 0)
    __hip_atomic_store(&flags[(size_t)b * 2 * FSTR], 1u, __ATOMIC_RELAXED,
                       __HIP_MEMORY_SCOPE_AGENT);  // done flag (t=0 region)
  if (w == 0) {
    bool ok;
    do {
      u32 v0 = __hip_atomic_load(flags + (size_t)(lane * 4 + 0) * 2 * FSTR, __ATOMIC_RELAXED, __HIP_MEMORY_SCOPE_AGENT);
      u32 v1 = __hip_atomic_load(flags + (size_t)(lane * 4 + 1) * 2 * FSTR, __ATOMIC_RELAXED, __HIP_MEMORY_SCOPE_AGENT);
      u32 v2 = __hip_atomic_load(flags + (size_t)(lane * 4 + 2) * 2 * FSTR, __ATOMIC_RELAXED, __HIP_MEMORY_SCOPE_AGENT);
      u32 v3 = __hip_atomic_load(flags + (size_t)(lane * 4 + 3) * 2 * FSTR, __ATOMIC_RELAXED, __HIP_MEMORY_SCOPE_AGENT);
      ok = ((v0 & v1 & v2 & v3) == 1u);
      if (!__all(ok)) __builtin_amdgcn_s_sleep(1);
    } while (!__all(ok));
  }
  __syncthreads();

  // block b: slab ts = b>>1, rows [r0, r0+32). zo slab layout makes the
  // needed 4 cols of one producer block CONTIGUOUS: float4 per (r, c4).
  {
    const int ts = b >> 1;
    const int r0 = (b & 1) * 32;
#pragma unroll 4
    for (int it = 0; it < 16; ++it) {
      int flat = it * 512 + tid;    // 8192 float4 chunks
      int r = flat >> 8;            // 0..31
      int c4 = flat & 255;          // producer block index
      const u64* p = reinterpret_cast<const u64*>(
          zo + ((size_t)ts * 256 + c4) * 256 + (size_t)(r0 + r) * 4);
      u64 lo = __hip_atomic_load(p + 0, __ATOMIC_RELAXED, __HIP_MEMORY_SCOPE_AGENT);
      u64 hi = __hip_atomic_load(p + 1, __ATOMIC_RELAXED, __HIP_MEMORY_SCOPE_AGENT);
      float4 v;
      v.x = __builtin_bit_cast(float, (u32)lo);
      v.y = __builtin_bit_cast(float, (u32)(lo >> 32));
      v.z = __builtin_bit_cast(float, (u32)hi);
      v.w = __builtin_bit_cast(float, (u32)(hi >> 32));
      *reinterpret_cast<float4*>(
          out + ((size_t)(r0 + r) * NT + ts) * NH + c4 * 4) = v;
    }
  }
}

extern "C" void kernel_launch(void* const* d_in, const int* in_sizes, int n_in,
                              void* d_out, int out_size, void* d_ws, size_t ws_size,
                              hipStream_t stream) {
  const float* x = (const float*)d_in[0];
  const float* W = (const float*)d_in[1];
  const float* bias = (const float*)d_in[2];
  float* out = (float*)d_out;

  char* ws = (char*)d_ws;
  u16* xb = (u16*)(ws);                                  // 16 MiB
  u16* wt_blk = (u16*)(ws + 16777216);                   // 32 MiB
  u16* hseq = (u16*)(ws + 50331648);                     // 16 MiB (slab layout)
  u32* flags = (u32*)(ws + 67108864);                    // 4 MiB (2 per block, line-padded)
  float* zo = (float*)(ws + 71303168);                   // 32 MiB (block-slab staging)

  hipMemsetAsync(hseq, 0, 256 * 512, stream);                        // h_0 slabs = 0
  hipMemsetAsync(flags, 0, (size_t)NT * 512 * FSTR * 4, stream);     // per-replay

  lstm_cvt_x<<<(NB * NT * NF) / (256 * 4), 256, 0, stream>>>(x, xb);
  lstm_prep_w<<<dim3(NG / 32, NK / 32), 256, 0, stream>>>(W, wt_blk);

  hipFuncSetAttribute((const void*)lstm_persist,
                      hipFuncAttributeMaxDynamicSharedMemorySize, SMEM_BYTES);

  void* args[] = {(void*)&xb, (void*)&hseq, (void*)&wt_blk, (void*)&bias,
                  (void*)&out, (void*)&flags, (void*)&zo};
  hipLaunchCooperativeKernel((void*)lstm_persist, dim3(256), dim3(512), args,
                             SMEM_BYTES, stream);
}

// Round 19
// 1096.965 us; speedup vs baseline: 1.1673x; 1.1673x over previous
//
#include <hip/hip_runtime.h>
#include <hip/hip_bf16.h>

typedef unsigned short u16;
typedef unsigned int u32;
typedef unsigned long long u64;
typedef __bf16 bf16x8 __attribute__((ext_vector_type(8)));
typedef float f32x4 __attribute__((ext_vector_type(4)));

#define NB 64
#define NT 128
#define NF 1024
#define NH 1024
#define NK 2048
#define NG 4096
#define NBH (NB * NH)

#define FSTR 16   // flags: one u32 per 64B line

// LDS: W slice 128 KiB + zsx[2 buf][2][64][17] + zsh[2][64][17] + handshake
#define W_LDS_BYTES 131072
#define ZSX_BYTES (2 * 2 * 64 * 17 * 4)   // 17408
#define ZSH_BYTES (2 * 64 * 17 * 4)       // 8704
#define SMEM_BYTES (W_LDS_BYTES + ZSX_BYTES + ZSH_BYTES + 64)  // 157248

__device__ __forceinline__ u16 f2bf(float f) {
  unsigned u = __builtin_bit_cast(unsigned, f);
  u = (u + 0x7FFFu + ((u >> 16) & 1u)) >> 16;
  return (u16)u;
}
__device__ __forceinline__ float bf2f(u16 v) {
  unsigned u = ((unsigned)v) << 16;
  return __builtin_bit_cast(float, u);
}
// fast tanh: 1 - 2/(e^{2x}+1); exact limits at +-inf, err ~1e-7
__device__ __forceinline__ float ftanh(float x) {
  float e = __expf(2.f * x);
  return 1.f - 2.f / (e + 1.f);
}

// ---------------- prep: x fp32 -> bf16 ----------------
__global__ __launch_bounds__(256) void lstm_cvt_x(const float* __restrict__ x,
                                                  u16* __restrict__ xb) {
  int i = (blockIdx.x * 256 + threadIdx.x) * 4;
  float4 v = *reinterpret_cast<const float4*>(x + i);
  ushort4 o;
  o.x = f2bf(v.x); o.y = f2bf(v.y); o.z = f2bf(v.z); o.w = f2bf(v.w);
  *reinterpret_cast<ushort4*>(xb + i) = o;
}

// ---------------- prep: W -> per-block LDS-image slices (verified R3-R15) ----
__global__ __launch_bounds__(256) void lstm_prep_w(const float* __restrict__ W,
                                                   u16* __restrict__ wt_blk) {
  __shared__ float tile[32][33];
  int n0 = blockIdx.x * 32;
  int k0 = blockIdx.y * 32;
  int tc = threadIdx.x & 31;
  int tr = threadIdx.x >> 5;
#pragma unroll
  for (int i = 0; i < 4; ++i) {
    int k = tr + i * 8;
    tile[k][tc] = W[(size_t)(k0 + k) * NG + n0 + tc];
  }
  __syncthreads();
#pragma unroll
  for (int i = 0; i < 4; ++i) {
    int n = n0 + tr + i * 8;
    float wv = tile[tc][tr + i * 8];
    int k = k0 + tc;
    int g = n >> 10, col = n & 1023;
    int b = col >> 2, brow = g * 4 + (col & 3);
    int kh = k >> 10, ch = (k & 1023) >> 5;
    int slot = (k >> 3) & 3, elem = k & 7;
    size_t base = (size_t)b * 65536 + (size_t)(kh * 32 + ch) * 512
                + (size_t)(slot * 16 + brow) * 8 + elem;
    u16 hi = f2bf(wv);
    wt_blk[base] = hi;
    wt_blk[base + 32768] = f2bf(wv - bf2f(hi));
  }
}

// x A-pass: 4 M-frags, K=256 slice, hi+lo MFMA, 2-stage pipeline (verified).
__device__ __forceinline__ void mfma_pass(const u16* __restrict__ a0, size_t rstride,
                                          const u16* __restrict__ Wl, int khalf,
                                          int kq, int lane, f32x4 acc[4]) {
  bf16x8 pf[4], qf[4];
#pragma unroll
  for (int i = 0; i < 4; ++i)
    pf[i] = *reinterpret_cast<const bf16x8*>(a0 + (size_t)i * 16 * rstride);
#pragma unroll
  for (int cc = 0; cc < 8; ++cc) {
    if (cc < 7) {
#pragma unroll
      for (int i = 0; i < 4; ++i)
        qf[i] = *reinterpret_cast<const bf16x8*>(a0 + (size_t)i * 16 * rstride + (cc + 1) * 32);
    }
    const int ch = kq * 8 + cc;
    const bf16x8 wh = *reinterpret_cast<const bf16x8*>(
        Wl + (size_t)(khalf * 32 + ch) * 512 + lane * 8);
    const bf16x8 wl2 = *reinterpret_cast<const bf16x8*>(
        Wl + (size_t)(64 + khalf * 32 + ch) * 512 + lane * 8);
#pragma unroll
    for (int i = 0; i < 4; ++i)
      acc[i] = __builtin_amdgcn_mfma_f32_16x16x32_bf16(pf[i], wh, acc[i], 0, 0, 0);
#pragma unroll
    for (int i = 0; i < 4; ++i)
      acc[i] = __builtin_amdgcn_mfma_f32_16x16x32_bf16(pf[i], wl2, acc[i], 0, 0, 0);
#pragma unroll
    for (int i = 0; i < 4; ++i) pf[i] = qf[i];
  }
}

// ---------------- persistent LSTM (R15 base + block-slab zo + ftanh) -----------
// 256 blocks x 512 threads. Waves 0-3: x-GEMM one step ahead (zsx dbuf).
// Waves 4-7: poll 64 producer flags (line-padded, paced) -> slab h load ->
// MFMA -> zsh write/add (3 barriers). Pointwise on tid<128; slab-coalesced h
// publish (512 B / 8 lines per block), vmcnt(0), LDS handshake, ONE flag.
// zo staging per-block contiguous (1 KiB/block/step -> 16 lines, was 256).
__global__ __launch_bounds__(512) void lstm_persist(
    const u16* __restrict__ xb, u16* __restrict__ hseq,
    const u16* __restrict__ wt_blk, const float* __restrict__ bias,
    float* __restrict__ out, u32* __restrict__ flags,
    float* __restrict__ zo) {
  extern __shared__ char smem[];
  u16* Wl = (u16*)smem;
  float (*zsx)[2][64][17] = (float(*)[2][64][17])(smem + W_LDS_BYTES);
  float (*zsh)[64][17] = (float(*)[64][17])(smem + W_LDS_BYTES + ZSX_BYTES);
  volatile u32* hsflag = (volatile u32*)(smem + W_LDS_BYTES + ZSX_BYTES + ZSH_BYTES);

  const int b = blockIdx.x;
  const int tid = threadIdx.x;
  const int lane = tid & 63;
  const int w = tid >> 6;
  const bool is_x = (w < 4);
  const int kq = w & 3;

  // ---- load W slice (128 KiB) into LDS ----
  {
    const u16* src = wt_blk + (size_t)b * 65536;
#pragma unroll
    for (int it = 0; it < 16; ++it) {
      uint4 v = *reinterpret_cast<const uint4*>(src + (size_t)it * 4096 + tid * 8);
      *reinterpret_cast<uint4*>(Wl + (size_t)it * 4096 + tid * 8) = v;
    }
  }
  for (int i = tid; i < 2 * 64 * 17; i += 512) ((float*)zsh)[i] = 0.f;
  if (tid == 0) hsflag[0] = 0u;

  const int arow = lane & 15;
  const int kfr = 8 * (lane >> 4);
  const int kbase = kq * 256 + kfr;
  const int zn = lane & 15;
  const int mg = (lane >> 4) * 4;

  // pointwise ownership: tid<128 owns (prow, 2 cols)
  const int prow = tid >> 1;
  const int pc = (tid & 1) * 2;
  const int gc0 = b * 4 + pc;
  float bz[2][4];
  float creg[2] = {0.f, 0.f};
  if (tid < 128) {
#pragma unroll
    for (int j = 0; j < 2; ++j) {
      bz[j][0] = bias[gc0 + j];
      bz[j][1] = bias[NH + gc0 + j];
      bz[j][2] = bias[2 * NH + gc0 + j];
      bz[j][3] = bias[3 * NH + gc0 + j];
    }
  }
  __syncthreads();

  // ---- prologue: x-waves fill zsx[0] = zx(0) ----
  {
    f32x4 acc[4] = {};
    if (is_x) {
      const u16* a0 = xb + ((size_t)arow * NT + 0) * NF + kbase;
      mfma_pass(a0, (size_t)NT * NF, Wl, 0, kq, lane, acc);
      if (w < 2) {
#pragma unroll
        for (int i = 0; i < 4; ++i)
#pragma unroll
          for (int r = 0; r < 4; ++r) zsx[0][w][i * 16 + mg + r][zn] = acc[i][r];
      }
    }
    __syncthreads();
    if (is_x && w >= 2) {
#pragma unroll
      for (int i = 0; i < 4; ++i)
#pragma unroll
        for (int r = 0; r < 4; ++r) zsx[0][w - 2][i * 16 + mg + r][zn] += acc[i][r];
    }
    __syncthreads();
  }

#pragma unroll 1
  for (int t = 0; t < NT; ++t) {
    const int cb = t & 1;        // zsx buffer consumed this step
    const int nb = (t + 1) & 1;  // zsx buffer filled this step
    f32x4 acc[4] = {};

    if (is_x) {
      if (t < NT - 1) {
        const u16* a0 = xb + ((size_t)arow * NT + (t + 1)) * NF + kbase;
        mfma_pass(a0, (size_t)NT * NF, Wl, 0, kq, lane, acc);
      }
    } else {
      if (t > 0) {
        // dataflow poll (line-padded flags, paced): producers [64kq, 64kq+64)
        const u32* fp = flags + ((size_t)t * 256 + kq * 64 + lane) * FSTR;
        u32 v = __hip_atomic_load(fp, __ATOMIC_RELAXED, __HIP_MEMORY_SCOPE_AGENT);
        while (!__all(v != 0)) {
          __builtin_amdgcn_s_sleep(1);
          v = __hip_atomic_load(fp, __ATOMIC_RELAXED, __HIP_MEMORY_SCOPE_AGENT);
        }

        // ---- slab-layout h-GEMM (verified R14/R15) ----
        const u64* hb = reinterpret_cast<const u64*>(hseq) + (size_t)t * (256 * 64);
        const int sbase = kq * 64 + 2 * (lane >> 4);
        u64 plo[4], phi[4], qlo[4], qhi[4];
#pragma unroll
        for (int i = 0; i < 4; ++i) {
          plo[i] = hb[(size_t)sbase * 64 + arow + 16 * i];
          phi[i] = hb[(size_t)(sbase + 1) * 64 + arow + 16 * i];
        }
        __builtin_amdgcn_s_setprio(1);
#pragma unroll
        for (int cc = 0; cc < 8; ++cc) {
          if (cc < 7) {
            const int s = sbase + (cc + 1) * 8;
#pragma unroll
            for (int i = 0; i < 4; ++i) {
              qlo[i] = hb[(size_t)s * 64 + arow + 16 * i];
              qhi[i] = hb[(size_t)(s + 1) * 64 + arow + 16 * i];
            }
          }
          const int ch = kq * 8 + cc;
          const bf16x8 wh = *reinterpret_cast<const bf16x8*>(
              Wl + (size_t)(32 + ch) * 512 + lane * 8);             // kh=1 hi
          const bf16x8 wlo = *reinterpret_cast<const bf16x8*>(
              Wl + (size_t)(96 + ch) * 512 + lane * 8);             // kh=1 lo
#pragma unroll
          for (int i = 0; i < 4; ++i) {
            union HU { u64 q[2]; bf16x8 f; } u;
            u.q[0] = plo[i];
            u.q[1] = phi[i];
            acc[i] = __builtin_amdgcn_mfma_f32_16x16x32_bf16(u.f, wh, acc[i], 0, 0, 0);
            acc[i] = __builtin_amdgcn_mfma_f32_16x16x32_bf16(u.f, wlo, acc[i], 0, 0, 0);
          }
#pragma unroll
          for (int i = 0; i < 4; ++i) { plo[i] = qlo[i]; phi[i] = qhi[i]; }
        }
        __builtin_amdgcn_s_setprio(0);
      }
    }

    // ---- write phase ----
    if (is_x) {
      if (w < 2 && t < NT - 1) {
#pragma unroll
        for (int i = 0; i < 4; ++i)
#pragma unroll
          for (int r = 0; r < 4; ++r) zsx[nb][w][i * 16 + mg + r][zn] = acc[i][r];
      }
    } else {
      if (w < 6 && t > 0) {
#pragma unroll
        for (int i = 0; i < 4; ++i)
#pragma unroll
          for (int r = 0; r < 4; ++r) zsh[w - 4][i * 16 + mg + r][zn] = acc[i][r];
      }
    }
    __syncthreads();
    // ---- add phase ----
    if (is_x) {
      if (w >= 2 && t < NT - 1) {
#pragma unroll
        for (int i = 0; i < 4; ++i)
#pragma unroll
          for (int r = 0; r < 4; ++r) zsx[nb][w - 2][i * 16 + mg + r][zn] += acc[i][r];
      }
    } else {
      if (w >= 6 && t > 0) {
#pragma unroll
        for (int i = 0; i < 4; ++i)
#pragma unroll
          for (int r = 0; r < 4; ++r) zsh[w - 6][i * 16 + mg + r][zn] += acc[i][r];
      }
    }
    __syncthreads();

    // ---- fused pointwise + coalesced h publish + block-slab staged output ----
    if (tid < 128) {
      float hn[2];
#pragma unroll
      for (int jj = 0; jj < 2; ++jj) {
        const int col = pc + jj;
        const float zi = zsx[cb][0][prow][col]      + zsx[cb][1][prow][col]      + zsh[0][prow][col]      + zsh[1][prow][col]      + bz[jj][0];
        const float zj = zsx[cb][0][prow][4 + col]  + zsx[cb][1][prow][4 + col]  + zsh[0][prow][4 + col]  + zsh[1][prow][4 + col]  + bz[jj][1];
        const float zf = zsx[cb][0][prow][8 + col]  + zsx[cb][1][prow][8 + col]  + zsh[0][prow][8 + col]  + zsh[1][prow][8 + col]  + bz[jj][2];
        const float zo4 = zsx[cb][0][prow][12 + col] + zsx[cb][1][prow][12 + col] + zsh[0][prow][12 + col] + zsh[1][prow][12 + col] + bz[jj][3];
        const float si = 1.f / (1.f + __expf(-zi));
        const float tj = ftanh(zj);
        const float sf = 1.f / (1.f + __expf(-(zf + 1.0f)));  // FORGET_BIAS = 1
        const float so = 1.f / (1.f + __expf(-zo4));
        const float cn = creg[jj] * sf + si * tj;
        hn[jj] = ftanh(cn) * so;
        creg[jj] = cn;
      }
      if (t < NT - 1) {
        // h publish: SLAB layout -> 128 consecutive u32 = 512 B, 8 LLC lines
        u32 hv = (u32)f2bf(hn[0]) | ((u32)f2bf(hn[1]) << 16);
        u32* hp = reinterpret_cast<u32*>(hseq)
                + ((size_t)(t + 1) * 256 + b) * 128 + prow * 2 + (pc >> 1);
        __hip_atomic_store(hp, hv, __ATOMIC_RELAXED, __HIP_MEMORY_SCOPE_AGENT);
        asm volatile("s_waitcnt vmcnt(0)" ::: "memory");  // 8-line ack
        if (tid == 64) hsflag[0] = (u32)(t + 1);          // wave 1 drained
        if (tid == 0) {
          while (hsflag[0] != (u32)(t + 1)) {}            // wait wave 1
          __hip_atomic_store(&flags[((size_t)(t + 1) * 256 + b) * FSTR], 1u,
                             __ATOMIC_RELAXED, __HIP_MEMORY_SCOPE_AGENT);
        }
      }
      // staged output: per-block contiguous slab (1 KiB/step), u64 per thread
      {
        u64 dv;
        memcpy(&dv, hn, 8);
        __hip_atomic_store(
            reinterpret_cast<u64*>(zo + ((size_t)t * 256 + b) * 256 + prow * 4 + pc),
            dv, __ATOMIC_RELAXED, __HIP_MEMORY_SCOPE_AGENT);
      }
    }
    // h-waves proceed to poll step t+1 while waves 0-1 finish the tail
  }

  // ================= final: grid rendezvous, then zo -> out copy ==============
  __syncthreads();
  asm volatile("s_waitcnt vmcnt(0)" ::: "memory");  // all zo stores at LLC
  if (tid == 0)
    __hip_atomic_store(&flags[(size_t)b * FSTR], 1u, __ATOMIC_RELAXED,
                       __HIP_MEMORY_SCOPE_AGENT);  // done flag (t=0 region)
  if (w == 0) {
    bool ok;
    do {
      u32 v0 = __hip_atomic_load(flags + (size_t)(lane * 4 + 0) * FSTR, __ATOMIC_RELAXED, __HIP_MEMORY_SCOPE_AGENT);
      u32 v1 = __hip_atomic_load(flags + (size_t)(lane * 4 + 1) * FSTR, __ATOMIC_RELAXED, __HIP_MEMORY_SCOPE_AGENT);
      u32 v2 = __hip_atomic_load(flags + (size_t)(lane * 4 + 2) * FSTR, __ATOMIC_RELAXED, __HIP_MEMORY_SCOPE_AGENT);
      u32 v3 = __hip_atomic_load(flags + (size_t)(lane * 4 + 3) * FSTR, __ATOMIC_RELAXED, __HIP_MEMORY_SCOPE_AGENT);
      ok = ((v0 & v1 & v2 & v3) == 1u);
      if (!__all(ok)) __builtin_amdgcn_s_sleep(1);
    } while (!__all(ok));
  }
  __syncthreads();

  // block b: slab ts = b>>1, rows [r0, r0+32). zo block-slab layout makes the
  // needed 4 cols of one producer block CONTIGUOUS: float4 per (r, c4).
  {
    const int ts = b >> 1;
    const int r0 = (b & 1) * 32;
#pragma unroll 4
    for (int it = 0; it < 16; ++it) {
      int flat = it * 512 + tid;    // 8192 float4 chunks
      int r = flat >> 8;            // 0..31
      int c4 = flat & 255;          // producer block index
      const u64* p = reinterpret_cast<const u64*>(
          zo + ((size_t)ts * 256 + c4) * 256 + (size_t)(r0 + r) * 4);
      u64 lo = __hip_atomic_load(p + 0, __ATOMIC_RELAXED, __HIP_MEMORY_SCOPE_AGENT);
      u64 hi = __hip_atomic_load(p + 1, __ATOMIC_RELAXED, __HIP_MEMORY_SCOPE_AGENT);
      float4 v;
      v.x = __builtin_bit_cast(float, (u32)lo);
      v.y = __builtin_bit_cast(float, (u32)(lo >> 32));
      v.z = __builtin_bit_cast(float, (u32)hi);
      v.w = __builtin_bit_cast(float, (u32)(hi >> 32));
      *reinterpret_cast<float4*>(
          out + ((size_t)(r0 + r) * NT + ts) * NH + c4 * 4) = v;
    }
  }
}

extern "C" void kernel_launch(void* const* d_in, const int* in_sizes, int n_in,
                              void* d_out, int out_size, void* d_ws, size_t ws_size,
                              hipStream_t stream) {
  const float* x = (const float*)d_in[0];
  const float* W = (const float*)d_in[1];
  const float* bias = (const float*)d_in[2];
  float* out = (float*)d_out;

  char* ws = (char*)d_ws;
  u16* xb = (u16*)(ws);                                  // 16 MiB
  u16* wt_blk = (u16*)(ws + 16777216);                   // 32 MiB
  u16* hseq = (u16*)(ws + 50331648);                     // 16 MiB (slab layout)
  u32* flags = (u32*)(ws + 67108864);                    // 2 MiB (line-padded)
  float* zo = (float*)(ws + 69206016);                   // 32 MiB (block-slab staging)

  hipMemsetAsync(hseq, 0, 256 * 512, stream);                       // h_0 slabs = 0
  hipMemsetAsync(flags, 0, (size_t)NT * 256 * FSTR * 4, stream);    // per-replay

  lstm_cvt_x<<<(NB * NT * NF) / (256 * 4), 256, 0, stream>>>(x, xb);
  lstm_prep_w<<<dim3(NG / 32, NK / 32), 256, 0, stream>>>(W, wt_blk);

  hipFuncSetAttribute((const void*)lstm_persist,
                      hipFuncAttributeMaxDynamicSharedMemorySize, SMEM_BYTES);

  void* args[] = {(void*)&xb, (void*)&hseq, (void*)&wt_blk, (void*)&bias,
                  (void*)&out, (void*)&flags, (void*)&zo};
  hipLaunchCooperativeKernel((void*)lstm_persist, dim3(256), dim3(512), args,
                             SMEM_BYTES, stream);
}